// Round 20
// baseline (5772.656 us; speedup 1.0000x reference)
//
#include <hip/hip_runtime.h>

// Text2Vec: ctx[b] = cos(ctx[b] @ emb[ids[b,s]]), s = 0..8191.
// R19 = R18 monolithic-asm loop, TWO rows per wave (256 waves, 1/CU):
// the two rows share every E fetch (L1 floor halves) and their chains/cos
// interleave instruction-by-instruction to fill all dep-latency bubbles
// (R18 at 1 wave/SIMD had nothing to fill them with). Per row per step:
// acc = sum_j readlane(v,j)*E[j][c], ascending j, single accumulator,
// v_fmac == host fmaf chain bit-exactly; cos = glibc-cosf replica ported
// op-for-op to f64 asm (proven bit-exact R18). E in v[64:127], refill per
// quad gated by counted vmcnt(15) (FIFO). id stream: in-asm s_load, 1 step
// ahead. Step 0 peeled in C (I@E0 row == E0 row; cos(+-0)=1 both).

#define BB 8
#define SS 8192
#define DD 64

// ---- branchless bit-exact replica of glibc cosf (C version, epilogue) ----
__device__ __forceinline__ float host_cosf(float y)
{
#pragma clang fp contract(off)
    const double hpi_inv = 0x1.45F306DC9C883p+23;
    const double hpi     = 0x1.921FB54442D18p0;
    const double c0 = 0x1p0;
    const double c1 = -0x1.ffffffd0c621cp-2;
    const double c2 = 0x1.55553e1068f19p-5;
    const double c3 = -0x1.6c087e89a359dp-10;
    const double c4 = 0x1.99343027bf8c3p-16;
    const double s1 = -0x1.555545995a603p-3;
    const double s2 = 0x1.1107605230bc4p-7;
    const double s3 = -0x1.994eb3774cf24p-13;

    const double x = (double)y;
    double r  = x * hpi_inv;
    int    n  = (((int)r) + 0x800000) >> 24;
    double xr = fma(-(double)n, hpi, x);

    const int  mm   = (n + 1) & 3;
    const double s  = (mm == 1 || mm == 2) ? -1.0 : 1.0;
    const bool negt = (mm & 2) != 0;

    double x2  = xr * xr;
    double x4  = x2 * x2;
    double cc2 = fma(x2, c4, c3);
    double cc1 = fma(x2, c1, c0);
    double x6  = x4 * x2;
    double cp  = fma(x4, c2, cc1);
    float fcos = (float)fma(x6, cc2, cp);
    fcos = negt ? -fcos : fcos;

    double xs  = xr * s;
    double x3  = xs * x2;
    double sp1 = fma(x2, s3, s2);
    double x7  = x3 * x2;
    double sr  = fma(x3, s1, xs);
    float fsin = (float)fma(x7, sp1, sr);

    return (n & 1) ? fsin : fcos;
}

// one-time: embT[id][(j>>2)*256 + c*4 + (j&3)] = emb[id][j*64 + c].
__global__ void transpose_kernel(const float* __restrict__ emb,
                                 float* __restrict__ embT)
{
    const int id = blockIdx.x;
    const int t  = threadIdx.x;
    const float* src = emb + (size_t)id * (DD * DD);
    float*       dst = embT + (size_t)id * (DD * DD);
#pragma unroll
    for (int kk = 0; kk < 16; ++kk) {
        const int lin = kk * 256 + t;
        const int j = lin >> 6, c = lin & 63;
        dst[(j >> 2) * 256 + c * 4 + (j & 3)] = src[lin];
    }
}

// ---- monolith building blocks ----
#define RLA(S,J)   "v_readlane_b32 s" #S ", %[vra], " #J "\n\t"
#define RLB(S,J)   "v_readlane_b32 s" #S ", %[vrb], " #J "\n\t"
#define FMA_(S,E)  "v_fmac_f32 %[aca], s" #S ", v" #E "\n\t"
#define FMB_(S,E)  "v_fmac_f32 %[acb], s" #S ", v" #E "\n\t"
// dual slot: both rows consume e-reg E, then prefetch lane J into temps
#define DSLOT(SA,SB,E,J)  FMA_(SA,E) FMB_(SB,E) RLA(SA,J) RLB(SB,J)
#define DSLOTN(SA,SB,E)   FMA_(SA,E) FMB_(SB,E)
#define WQ         "s_waitcnt vmcnt(15)\n\t"
#define LDQ(D0,D3,VO,OFF) \
    "global_load_dwordx4 v[" #D0 ":" #D3 "], " VO ", s[46:47] offset:" OFF "\n\t"

__global__ __launch_bounds__(64, 1)
void text2vec_kernel(const int* __restrict__ ids,
                     const float* __restrict__ emb,    // original layout (peel)
                     const float* __restrict__ embT,   // transposed table
                     float* __restrict__ out)
{
    const int blk  = blockIdx.x;
    const int b    = blk & 7;
    const int rp   = blk >> 3;            // row pair 0..31
    const int r0   = rp * 2, r1 = rp * 2 + 1;
    const int lane = threadIdx.x;

    const int* bids = ids + b * SS;
    const uintptr_t ta = (uintptr_t)embT;
    const unsigned tlo = (unsigned)ta, thi = (unsigned)(ta >> 32);
    unsigned vo0 = (unsigned)lane * 16u;
    unsigned vo1 = vo0 + 4096u, vo2 = vo0 + 8192u, vo3 = vo0 + 12288u;

    const int id0 = bids[0], id1 = bids[1], id2 = bids[2];

    // step-0 peel (both rows): acc = E(0)[r][lane]; only +-0 differs vs the
    // fmaf chain and cos(+-0) = 1.0f either way.
    float aca = emb[(size_t)(unsigned)id0 * (DD * DD) + r0 * DD + lane];
    float acb = emb[(size_t)(unsigned)id0 * (DD * DD) + r1 * DD + lane];
    float vra = 0.0f, vrb = 0.0f;

    const double d_hpinv = 0x1.45F306DC9C883p+23;
    const double d_hpi   = 0x1.921FB54442D18p0;
    const double d_c0 = 0x1p0;
    const double d_c1 = -0x1.ffffffd0c621cp-2;
    const double d_c2 = 0x1.55553e1068f19p-5;
    const double d_c3 = -0x1.6c087e89a359dp-10;
    const double d_c4 = 0x1.99343027bf8c3p-16;
    const double d_s1 = -0x1.555545995a603p-3;
    const double d_s2 = 0x1.1107605230bc4p-7;
    const double d_s3 = -0x1.994eb3774cf24p-13;

    asm volatile(
        // ---------- prologue: E(1) -> v[64:127]; id pipeline ----------
        "s_lshl_b32 s44, %[id1], 14\n\t"
        "s_add_u32 s46, %[tlo], s44\n\t"
        "s_addc_u32 s47, %[thi], 0\n\t"
        LDQ(64,67,"%[vo0]","0")    LDQ(68,71,"%[vo0]","1024")
        LDQ(72,75,"%[vo0]","2048") LDQ(76,79,"%[vo0]","3072")
        LDQ(80,83,"%[vo1]","0")    LDQ(84,87,"%[vo1]","1024")
        LDQ(88,91,"%[vo1]","2048") LDQ(92,95,"%[vo1]","3072")
        LDQ(96,99,"%[vo2]","0")    LDQ(100,103,"%[vo2]","1024")
        LDQ(104,107,"%[vo2]","2048") LDQ(108,111,"%[vo2]","3072")
        LDQ(112,115,"%[vo3]","0")  LDQ(116,119,"%[vo3]","1024")
        LDQ(120,123,"%[vo3]","2048") LDQ(124,127,"%[vo3]","3072")
        "s_mov_b32 s41, %[id2]\n\t"
        "s_mov_b32 s40, 1\n\t"

        "T2V_LOOP:\n\t"
        // ---------- dual cos (a: v8-27, b: v28-47), interleaved ----------
        "v_cvt_f64_f32 v[8:9], %[aca]\n\t"
        "v_cvt_f64_f32 v[28:29], %[acb]\n\t"
        "v_mul_f64 v[10:11], v[8:9], %[hpinv]\n\t"
        "v_mul_f64 v[30:31], v[28:29], %[hpinv]\n\t"
        "v_cvt_i32_f64 v12, v[10:11]\n\t"
        "v_cvt_i32_f64 v32, v[30:31]\n\t"
        "v_add_u32 v12, 0x800000, v12\n\t"
        "v_add_u32 v32, 0x800000, v32\n\t"
        "v_ashrrev_i32 v12, 24, v12\n\t"
        "v_ashrrev_i32 v32, 24, v32\n\t"
        "v_cvt_f64_i32 v[10:11], v12\n\t"
        "v_cvt_f64_i32 v[30:31], v32\n\t"
        "v_fma_f64 v[8:9], -v[10:11], %[hpi], v[8:9]\n\t"
        "v_fma_f64 v[28:29], -v[30:31], %[hpi], v[28:29]\n\t"
        "v_add_u32 v13, 1, v12\n\t"
        "v_add_u32 v33, 1, v32\n\t"
        "v_and_b32 v14, 2, v13\n\t"
        "v_and_b32 v34, 2, v33\n\t"
        "v_cmp_ne_u32 s[56:57], 0, v14\n\t"           // negt_a
        "v_cmp_ne_u32 s[58:59], 0, v34\n\t"           // negt_b
        "v_and_b32 v14, 3, v13\n\t"
        "v_and_b32 v34, 3, v33\n\t"
        "v_add_u32 v14, 1, v14\n\t"
        "v_add_u32 v34, 1, v34\n\t"
        "v_and_b32 v14, 2, v14\n\t"
        "v_and_b32 v34, 2, v34\n\t"
        "v_cmp_ne_u32 s[36:37], 0, v14\n\t"           // ssel_a
        "v_cmp_ne_u32 s[38:39], 0, v34\n\t"           // ssel_b
        "v_mov_b32 v14, 0x3ff00000\n\t"
        "v_mov_b32 v15, 0xbff00000\n\t"
        "v_cndmask_b32 v15, v14, v15, s[36:37]\n\t"
        "v_mov_b32 v34, 0x3ff00000\n\t"
        "v_mov_b32 v35, 0xbff00000\n\t"
        "v_cndmask_b32 v35, v34, v35, s[38:39]\n\t"
        "v_mov_b32 v14, 0\n\t"
        "v_mov_b32 v34, 0\n\t"
        "v_mul_f64 v[16:17], v[8:9], v[8:9]\n\t"
        "v_mul_f64 v[36:37], v[28:29], v[28:29]\n\t"
        "v_mul_f64 v[18:19], v[16:17], v[16:17]\n\t"
        "v_mul_f64 v[38:39], v[36:37], v[36:37]\n\t"
        "v_fma_f64 v[20:21], v[16:17], %[c4], %[c3]\n\t"
        "v_fma_f64 v[40:41], v[36:37], %[c4], %[c3]\n\t"
        "v_fma_f64 v[22:23], v[16:17], %[c1], %[c0]\n\t"
        "v_fma_f64 v[42:43], v[36:37], %[c1], %[c0]\n\t"
        "v_mul_f64 v[24:25], v[18:19], v[16:17]\n\t"
        "v_mul_f64 v[44:45], v[38:39], v[36:37]\n\t"
        "v_fma_f64 v[22:23], v[18:19], %[c2], v[22:23]\n\t"
        "v_fma_f64 v[42:43], v[38:39], %[c2], v[42:43]\n\t"
        "v_fma_f64 v[20:21], v[24:25], v[20:21], v[22:23]\n\t"
        "v_fma_f64 v[40:41], v[44:45], v[40:41], v[42:43]\n\t"
        "v_cvt_f32_f64 v26, v[20:21]\n\t"
        "v_cvt_f32_f64 v46, v[40:41]\n\t"
        "v_xor_b32 v27, 0x80000000, v26\n\t"
        "v_xor_b32 v47, 0x80000000, v46\n\t"
        "v_cndmask_b32 v26, v26, v27, s[56:57]\n\t"
        "v_cndmask_b32 v46, v46, v47, s[58:59]\n\t"
        "v_mul_f64 v[18:19], v[8:9], v[14:15]\n\t"
        "v_mul_f64 v[38:39], v[28:29], v[34:35]\n\t"
        "v_mul_f64 v[20:21], v[18:19], v[16:17]\n\t"
        "v_mul_f64 v[40:41], v[38:39], v[36:37]\n\t"
        "v_fma_f64 v[22:23], v[16:17], %[s3], %[s2]\n\t"
        "v_fma_f64 v[42:43], v[36:37], %[s3], %[s2]\n\t"
        "v_mul_f64 v[24:25], v[20:21], v[16:17]\n\t"
        "v_mul_f64 v[44:45], v[40:41], v[36:37]\n\t"
        "v_fma_f64 v[18:19], v[20:21], %[s1], v[18:19]\n\t"
        "v_fma_f64 v[38:39], v[40:41], %[s1], v[38:39]\n\t"
        "v_fma_f64 v[18:19], v[24:25], v[22:23], v[18:19]\n\t"
        "v_fma_f64 v[38:39], v[44:45], v[42:43], v[38:39]\n\t"
        "v_cvt_f32_f64 v27, v[18:19]\n\t"
        "v_cvt_f32_f64 v47, v[38:39]\n\t"
        "v_and_b32 v14, 1, v12\n\t"
        "v_and_b32 v34, 1, v32\n\t"
        "v_cmp_ne_u32 s[30:31], 0, v14\n\t"           // odd_a
        "v_cmp_ne_u32 s[32:33], 0, v34\n\t"           // odd_b
        "v_cndmask_b32 %[vra], v26, v27, s[30:31]\n\t"
        "v_cndmask_b32 %[vrb], v46, v47, s[32:33]\n\t"
        "v_mov_b32 %[aca], 0\n\t"
        "v_mov_b32 %[acb], 0\n\t"
        // ---------- scalar: pnext from s41; issue next id s_load ----------
        "s_waitcnt lgkmcnt(0)\n\t"
        "s_lshl_b32 s44, s41, 14\n\t"
        "s_add_u32 s46, %[tlo], s44\n\t"
        "s_addc_u32 s47, %[thi], 0\n\t"
        "s_add_u32 s43, s40, 2\n\t"
        "s_and_b32 s43, s43, 8191\n\t"
        "s_lshl_b32 s43, s43, 2\n\t"
        "s_load_dword s41, %[bids], s43\n\t"
        // ---------- dual chain: 128 fmac + 128 readlane, refill per quad ---
        RLA(50,0) RLB(60,0) RLA(51,1) RLB(61,1) RLA(52,2) RLB(62,2)
        RLA(53,3) RLB(63,3) RLA(54,4) RLB(64,4) RLA(55,5) RLB(65,5)
        WQ DSLOT(50,60,64,6)   DSLOT(51,61,65,7)   DSLOT(52,62,66,8)   DSLOT(53,63,67,9)   LDQ(64,67,"%[vo0]","0")
        WQ DSLOT(54,64,68,10)  DSLOT(55,65,69,11)  DSLOT(50,60,70,12)  DSLOT(51,61,71,13)  LDQ(68,71,"%[vo0]","1024")
        WQ DSLOT(52,62,72,14)  DSLOT(53,63,73,15)  DSLOT(54,64,74,16)  DSLOT(55,65,75,17)  LDQ(72,75,"%[vo0]","2048")
        WQ DSLOT(50,60,76,18)  DSLOT(51,61,77,19)  DSLOT(52,62,78,20)  DSLOT(53,63,79,21)  LDQ(76,79,"%[vo0]","3072")
        WQ DSLOT(54,64,80,22)  DSLOT(55,65,81,23)  DSLOT(50,60,82,24)  DSLOT(51,61,83,25)  LDQ(80,83,"%[vo1]","0")
        WQ DSLOT(52,62,84,26)  DSLOT(53,63,85,27)  DSLOT(54,64,86,28)  DSLOT(55,65,87,29)  LDQ(84,87,"%[vo1]","1024")
        WQ DSLOT(50,60,88,30)  DSLOT(51,61,89,31)  DSLOT(52,62,90,32)  DSLOT(53,63,91,33)  LDQ(88,91,"%[vo1]","2048")
        WQ DSLOT(54,64,92,34)  DSLOT(55,65,93,35)  DSLOT(50,60,94,36)  DSLOT(51,61,95,37)  LDQ(92,95,"%[vo1]","3072")
        WQ DSLOT(52,62,96,38)  DSLOT(53,63,97,39)  DSLOT(54,64,98,40)  DSLOT(55,65,99,41)  LDQ(96,99,"%[vo2]","0")
        WQ DSLOT(50,60,100,42) DSLOT(51,61,101,43) DSLOT(52,62,102,44) DSLOT(53,63,103,45) LDQ(100,103,"%[vo2]","1024")
        WQ DSLOT(54,64,104,46) DSLOT(55,65,105,47) DSLOT(50,60,106,48) DSLOT(51,61,107,49) LDQ(104,107,"%[vo2]","2048")
        WQ DSLOT(52,62,108,50) DSLOT(53,63,109,51) DSLOT(54,64,110,52) DSLOT(55,65,111,53) LDQ(108,111,"%[vo2]","3072")
        WQ DSLOT(50,60,112,54) DSLOT(51,61,113,55) DSLOT(52,62,114,56) DSLOT(53,63,115,57) LDQ(112,115,"%[vo3]","0")
        WQ DSLOT(54,64,116,58) DSLOT(55,65,117,59) DSLOT(50,60,118,60) DSLOT(51,61,119,61) LDQ(116,119,"%[vo3]","1024")
        WQ DSLOT(52,62,120,62) DSLOT(53,63,121,63) DSLOTN(54,64,122)   DSLOTN(55,65,123)   LDQ(120,123,"%[vo3]","2048")
        WQ DSLOTN(50,60,124)   DSLOTN(51,61,125)   DSLOTN(52,62,126)   DSLOTN(53,63,127)   LDQ(124,127,"%[vo3]","3072")
        // ---------- loop control ----------
        "s_addk_i32 s40, 1\n\t"
        "s_cmpk_lt_i32 s40, 0x2000\n\t"
        "s_cbranch_scc1 T2V_LOOP\n\t"
        "s_waitcnt vmcnt(0) lgkmcnt(0)\n\t"
        : [aca] "+v"(aca), [acb] "+v"(acb), [vra] "+v"(vra), [vrb] "+v"(vrb)
        : [tlo] "s"(tlo), [thi] "s"(thi), [bids] "s"(bids),
          [vo0] "v"(vo0), [vo1] "v"(vo1), [vo2] "v"(vo2), [vo3] "v"(vo3),
          [id1] "s"(id1), [id2] "s"(id2),
          [hpinv] "s"(d_hpinv), [hpi] "s"(d_hpi), [c4] "s"(d_c4),
          [c1] "s"(d_c1), [c2] "s"(d_c2), [s1] "s"(d_s1), [s3] "s"(d_s3),
          [c3] "v"(d_c3), [c0] "v"(d_c0), [s2] "v"(d_s2)
        : "memory", "scc", "vcc",
          "s30","s31","s32","s33","s36","s37","s38","s39",
          "s40","s41","s42","s43","s44","s45","s46","s47",
          "s50","s51","s52","s53","s54","s55","s56","s57","s58","s59",
          "s60","s61","s62","s63","s64","s65",
          "v8","v9","v10","v11","v12","v13","v14","v15","v16","v17",
          "v18","v19","v20","v21","v22","v23","v24","v25","v26","v27",
          "v28","v29","v30","v31","v32","v33","v34","v35","v36","v37",
          "v38","v39","v40","v41","v42","v43","v44","v45","v46","v47",
          "v64","v65","v66","v67","v68","v69","v70","v71",
          "v72","v73","v74","v75","v76","v77","v78","v79",
          "v80","v81","v82","v83","v84","v85","v86","v87",
          "v88","v89","v90","v91","v92","v93","v94","v95",
          "v96","v97","v98","v99","v100","v101","v102","v103",
          "v104","v105","v106","v107","v108","v109","v110","v111",
          "v112","v113","v114","v115","v116","v117","v118","v119",
          "v120","v121","v122","v123","v124","v125","v126","v127");

    // final cos + stores (proven C replica, bit-identical to the asm port)
    vra = host_cosf(aca);
    vrb = host_cosf(acb);
    out[b * (DD * DD) + r0 * DD + lane] = vra;
    out[b * (DD * DD) + r1 * DD + lane] = vrb;
}

extern "C" void kernel_launch(void* const* d_in, const int* in_sizes, int n_in,
                              void* d_out, int out_size, void* d_ws, size_t ws_size,
                              hipStream_t stream)
{
    const int*   ids = (const int*)  d_in[0];   // [B, S] int32
    const float* emb = (const float*)d_in[1];   // [V, D*D] f32
    float*       out = (float*)      d_out;     // [B, D, D] f32
    float*       embT = (float*)     d_ws;      // V*4096 floats (1.5 MB)

    const int V = in_sizes[1] / (DD * DD);

    transpose_kernel<<<dim3(V), dim3(256), 0, stream>>>(emb, embT);
    text2vec_kernel<<<dim3(BB * DD / 2), dim3(DD), 0, stream>>>(ids, emb, embT, out);
}

// Round 22
// 3111.406 us; speedup vs baseline: 1.8553x; 1.8553x over previous
//
#include <hip/hip_runtime.h>

// Text2Vec: ctx[b] = cos(ctx[b] @ emb[ids[b,s]]), s = 0..8191.
// 512 independent row-chains (8 batches x 64 rows), one wave per (b,row),
// lane c owns column c. acc = sum_j readlane(v,j)*E[j][c], ascending j,
// single accumulator, v_fmac == host fmaf chain bit-exactly; cos = glibc
// cosf replica ported op-for-op to f64 asm (bit-exact, R18-proven).
//
// R21 = R18 monolith + register double-banked E (v64-127 / v160-223):
// all 16 next-step GLDs issue at step top, interleaved into the dep-bound
// cos (fills the ~150 cyc of f64 bubbles at 1 wave/SIMD); the chain runs
// with ZERO interior waits behind one counted vmcnt(16) gate (FIFO: 32
// outstanding -> oldest 16 = current bank retired). Removes R18's 16
// in-chain WQ vmcnt(15) + refill scheduling. Loop unrolled x2 for bank
// parity; tail step 8191 on bank A gated vmcnt(0). R20's LDS-share
// experiment failed (absmax 2.0, defect not identified) -- reverted; this
// round reuses ONLY R18-proven mechanics.

#define BB 8
#define SS 8192
#define DD 64

// ---- branchless bit-exact replica of glibc cosf (C: peel + epilogue) ----
__device__ __forceinline__ float host_cosf(float y)
{
#pragma clang fp contract(off)
    const double hpi_inv = 0x1.45F306DC9C883p+23;
    const double hpi     = 0x1.921FB54442D18p0;
    const double c0 = 0x1p0;
    const double c1 = -0x1.ffffffd0c621cp-2;
    const double c2 = 0x1.55553e1068f19p-5;
    const double c3 = -0x1.6c087e89a359dp-10;
    const double c4 = 0x1.99343027bf8c3p-16;
    const double s1 = -0x1.555545995a603p-3;
    const double s2 = 0x1.1107605230bc4p-7;
    const double s3 = -0x1.994eb3774cf24p-13;

    const double x = (double)y;
    double r  = x * hpi_inv;
    int    n  = (((int)r) + 0x800000) >> 24;
    double xr = fma(-(double)n, hpi, x);

    const int  mm   = (n + 1) & 3;
    const double s  = (mm == 1 || mm == 2) ? -1.0 : 1.0;
    const bool negt = (mm & 2) != 0;

    double x2  = xr * xr;
    double x4  = x2 * x2;
    double cc2 = fma(x2, c4, c3);
    double cc1 = fma(x2, c1, c0);
    double x6  = x4 * x2;
    double cp  = fma(x4, c2, cc1);
    float fcos = (float)fma(x6, cc2, cp);
    fcos = negt ? -fcos : fcos;

    double xs  = xr * s;
    double x3  = xs * x2;
    double sp1 = fma(x2, s3, s2);
    double x7  = x3 * x2;
    double sr  = fma(x3, s1, xs);
    float fsin = (float)fma(x7, sp1, sr);

    return (n & 1) ? fsin : fcos;
}

// one-time: embT[id][(j>>2)*256 + c*4 + (j&3)] = emb[id][j*64 + c].
__global__ void transpose_kernel(const float* __restrict__ emb,
                                 float* __restrict__ embT)
{
    const int id = blockIdx.x;
    const int t  = threadIdx.x;
    const float* src = emb + (size_t)id * (DD * DD);
    float*       dst = embT + (size_t)id * (DD * DD);
#pragma unroll
    for (int kk = 0; kk < 16; ++kk) {
        const int lin = kk * 256 + t;
        const int j = lin >> 6, c = lin & 63;
        dst[(j >> 2) * 256 + c * 4 + (j & 3)] = src[lin];
    }
}

// ---- monolith building blocks ----
#define ROX(S,J)   "v_readlane_b32 s" #S ", %[vra], " #J "\n\t"
#define FRX(S,E,J) "v_fmac_f32 %[acc], s" #S ", v" #E "\n\t" \
                   "v_readlane_b32 s" #S ", %[vra], " #J "\n\t"
#define FOX(S,E)   "v_fmac_f32 %[acc], s" #S ", v" #E "\n\t"
#define GLD(D0,D3,VO,OFF) \
    "global_load_dwordx4 v[" #D0 ":" #D3 "], " VO ", s[46:47] offset:" OFF "\n\t"

// 16 GLDs into bank A (v64-127) / bank B (v160-223)
#define GLDA_Q0 GLD(64,67,"%[vo0]","0")    GLD(68,71,"%[vo0]","1024") \
                GLD(72,75,"%[vo0]","2048") GLD(76,79,"%[vo0]","3072")
#define GLDA_Q1 GLD(80,83,"%[vo1]","0")    GLD(84,87,"%[vo1]","1024") \
                GLD(88,91,"%[vo1]","2048") GLD(92,95,"%[vo1]","3072")
#define GLDA_Q2 GLD(96,99,"%[vo2]","0")    GLD(100,103,"%[vo2]","1024") \
                GLD(104,107,"%[vo2]","2048") GLD(108,111,"%[vo2]","3072")
#define GLDA_Q3 GLD(112,115,"%[vo3]","0")  GLD(116,119,"%[vo3]","1024") \
                GLD(120,123,"%[vo3]","2048") GLD(124,127,"%[vo3]","3072")
#define GLDB_Q0 GLD(160,163,"%[vo0]","0")    GLD(164,167,"%[vo0]","1024") \
                GLD(168,171,"%[vo0]","2048") GLD(172,175,"%[vo0]","3072")
#define GLDB_Q1 GLD(176,179,"%[vo1]","0")    GLD(180,183,"%[vo1]","1024") \
                GLD(184,187,"%[vo1]","2048") GLD(188,191,"%[vo1]","3072")
#define GLDB_Q2 GLD(192,195,"%[vo2]","0")    GLD(196,199,"%[vo2]","1024") \
                GLD(200,203,"%[vo2]","2048") GLD(204,207,"%[vo2]","3072")
#define GLDB_Q3 GLD(208,211,"%[vo3]","0")    GLD(212,215,"%[vo3]","1024") \
                GLD(216,219,"%[vo3]","2048") GLD(220,223,"%[vo3]","3072")

// cos chunks (R18's exact instruction sequence, split at independent points)
#define COS_A "v_cvt_f64_f32 v[8:9], %[acc]\n\t"
#define COS_B "v_mul_f64 v[10:11], v[8:9], %[hpinv]\n\t" \
              "v_cvt_i32_f64 v12, v[10:11]\n\t" \
              "v_add_u32 v12, 0x800000, v12\n\t" \
              "v_ashrrev_i32 v12, 24, v12\n\t" \
              "v_cvt_f64_i32 v[10:11], v12\n\t" \
              "v_fma_f64 v[8:9], -v[10:11], %[hpi], v[8:9]\n\t"
#define COS_C "v_add_u32 v13, 1, v12\n\t" \
              "v_and_b32 v14, 2, v13\n\t" \
              "v_cmp_ne_u32 s[56:57], 0, v14\n\t" \
              "v_and_b32 v14, 3, v13\n\t" \
              "v_add_u32 v14, 1, v14\n\t" \
              "v_and_b32 v14, 2, v14\n\t" \
              "v_cmp_ne_u32 vcc, 0, v14\n\t" \
              "v_mov_b32 v14, 0x3ff00000\n\t" \
              "v_mov_b32 v15, 0xbff00000\n\t" \
              "v_cndmask_b32 v15, v14, v15, vcc\n\t" \
              "v_mov_b32 v14, 0\n\t"
#define COS_D "v_mul_f64 v[16:17], v[8:9], v[8:9]\n\t" \
              "v_mul_f64 v[18:19], v[16:17], v[16:17]\n\t" \
              "v_fma_f64 v[20:21], v[16:17], %[c4], %[c3]\n\t" \
              "v_fma_f64 v[22:23], v[16:17], %[c1], %[c0]\n\t" \
              "v_mul_f64 v[24:25], v[18:19], v[16:17]\n\t" \
              "v_fma_f64 v[22:23], v[18:19], %[c2], v[22:23]\n\t" \
              "v_fma_f64 v[20:21], v[24:25], v[20:21], v[22:23]\n\t" \
              "v_cvt_f32_f64 v26, v[20:21]\n\t" \
              "v_xor_b32 v27, 0x80000000, v26\n\t" \
              "v_cndmask_b32 v26, v26, v27, s[56:57]\n\t"
#define COS_E "v_mul_f64 v[18:19], v[8:9], v[14:15]\n\t" \
              "v_mul_f64 v[20:21], v[18:19], v[16:17]\n\t" \
              "v_fma_f64 v[22:23], v[16:17], %[s3], %[s2]\n\t" \
              "v_mul_f64 v[24:25], v[20:21], v[16:17]\n\t" \
              "v_fma_f64 v[18:19], v[20:21], %[s1], v[18:19]\n\t" \
              "v_fma_f64 v[18:19], v[24:25], v[22:23], v[18:19]\n\t" \
              "v_cvt_f32_f64 v27, v[18:19]\n\t" \
              "v_and_b32 v14, 1, v12\n\t" \
              "v_cmp_ne_u32 vcc, 0, v14\n\t" \
              "v_cndmask_b32 %[vra], v26, v27, vcc\n\t" \
              "v_mov_b32 %[acc], 0\n\t"

// scalar: drain prev s_load (lgkm), compute base from s41 = id(s+1)
#define BASECALC \
    "s_waitcnt lgkmcnt(0)\n\t" \
    "s_lshl_b32 s44, s41, 14\n\t" \
    "s_add_u32 s46, %[tlo], s44\n\t" \
    "s_addc_u32 s47, %[thi], 0\n\t"
// fetch ids[s40+2] into s41 (masked; drained at next step's BASECALC)
#define IDLOAD \
    "s_add_u32 s43, s40, 2\n\t" \
    "s_and_b32 s43, s43, 8191\n\t" \
    "s_lshl_b32 s43, s43, 2\n\t" \
    "s_load_dword s41, %[bids], s43\n\t"

// 64-j chain, bank A (v64-127), zero interior waits (R18's exact rotation)
#define CHAIN_A \
    ROX(50,0) ROX(51,1) ROX(52,2) ROX(53,3) ROX(54,4) ROX(55,5) \
    FRX(50,64,6)   FRX(51,65,7)   FRX(52,66,8)   FRX(53,67,9) \
    FRX(54,68,10)  FRX(55,69,11)  FRX(50,70,12)  FRX(51,71,13) \
    FRX(52,72,14)  FRX(53,73,15)  FRX(54,74,16)  FRX(55,75,17) \
    FRX(50,76,18)  FRX(51,77,19)  FRX(52,78,20)  FRX(53,79,21) \
    FRX(54,80,22)  FRX(55,81,23)  FRX(50,82,24)  FRX(51,83,25) \
    FRX(52,84,26)  FRX(53,85,27)  FRX(54,86,28)  FRX(55,87,29) \
    FRX(50,88,30)  FRX(51,89,31)  FRX(52,90,32)  FRX(53,91,33) \
    FRX(54,92,34)  FRX(55,93,35)  FRX(50,94,36)  FRX(51,95,37) \
    FRX(52,96,38)  FRX(53,97,39)  FRX(54,98,40)  FRX(55,99,41) \
    FRX(50,100,42) FRX(51,101,43) FRX(52,102,44) FRX(53,103,45) \
    FRX(54,104,46) FRX(55,105,47) FRX(50,106,48) FRX(51,107,49) \
    FRX(52,108,50) FRX(53,109,51) FRX(54,110,52) FRX(55,111,53) \
    FRX(50,112,54) FRX(51,113,55) FRX(52,114,56) FRX(53,115,57) \
    FRX(54,116,58) FRX(55,117,59) FRX(50,118,60) FRX(51,119,61) \
    FRX(52,120,62) FRX(53,121,63) FOX(54,122)    FOX(55,123) \
    FOX(50,124)    FOX(51,125)    FOX(52,126)    FOX(53,127)

// 64-j chain, bank B (v160-223)
#define CHAIN_B \
    ROX(50,0) ROX(51,1) ROX(52,2) ROX(53,3) ROX(54,4) ROX(55,5) \
    FRX(50,160,6)   FRX(51,161,7)   FRX(52,162,8)   FRX(53,163,9) \
    FRX(54,164,10)  FRX(55,165,11)  FRX(50,166,12)  FRX(51,167,13) \
    FRX(52,168,14)  FRX(53,169,15)  FRX(54,170,16)  FRX(55,171,17) \
    FRX(50,172,18)  FRX(51,173,19)  FRX(52,174,20)  FRX(53,175,21) \
    FRX(54,176,22)  FRX(55,177,23)  FRX(50,178,24)  FRX(51,179,25) \
    FRX(52,180,26)  FRX(53,181,27)  FRX(54,182,28)  FRX(55,183,29) \
    FRX(50,184,30)  FRX(51,185,31)  FRX(52,186,32)  FRX(53,187,33) \
    FRX(54,188,34)  FRX(55,189,35)  FRX(50,190,36)  FRX(51,191,37) \
    FRX(52,192,38)  FRX(53,193,39)  FRX(54,194,40)  FRX(55,195,41) \
    FRX(50,196,42)  FRX(51,197,43)  FRX(52,198,44)  FRX(53,199,45) \
    FRX(54,200,46)  FRX(55,201,47)  FRX(50,202,48)  FRX(51,203,49) \
    FRX(52,204,50)  FRX(53,205,51)  FRX(54,206,52)  FRX(55,207,53) \
    FRX(50,208,54)  FRX(51,209,55)  FRX(52,210,56)  FRX(53,211,57) \
    FRX(54,212,58)  FRX(55,213,59)  FRX(50,214,60)  FRX(51,215,61) \
    FRX(52,216,62)  FRX(53,217,63)  FOX(54,218)     FOX(55,219) \
    FOX(50,220)     FOX(51,221)     FOX(52,222)     FOX(53,223)

__global__ __launch_bounds__(64, 1)
void text2vec_kernel(const int* __restrict__ ids,
                     const float* __restrict__ emb,    // original layout (peel)
                     const float* __restrict__ embT,   // transposed table
                     float* __restrict__ out)
{
    const int blk  = blockIdx.x;
    const int b    = blk & 7;
    const int r    = blk >> 3;
    const int lane = threadIdx.x;

    const int* bids = ids + b * SS;
    const uintptr_t ta = (uintptr_t)embT;
    const unsigned tlo = (unsigned)ta, thi = (unsigned)(ta >> 32);
    unsigned vo0 = (unsigned)lane * 16u;
    unsigned vo1 = vo0 + 4096u, vo2 = vo0 + 8192u, vo3 = vo0 + 12288u;

    const int id0 = bids[0], id1 = bids[1], id2 = bids[2];

    // step-0 peel: acc = (I @ E(0))[r][lane] = E(0)[r][lane]; only +-0 can
    // differ vs the fmaf chain and cos(+-0)=1.0f either way.
    float acc  = emb[(size_t)(unsigned)id0 * (DD * DD) + r * DD + lane];
    float vra  = 0.0f;

    const double d_hpinv = 0x1.45F306DC9C883p+23;
    const double d_hpi   = 0x1.921FB54442D18p0;
    const double d_c0 = 0x1p0;
    const double d_c1 = -0x1.ffffffd0c621cp-2;
    const double d_c2 = 0x1.55553e1068f19p-5;
    const double d_c3 = -0x1.6c087e89a359dp-10;
    const double d_c4 = 0x1.99343027bf8c3p-16;
    const double d_s1 = -0x1.555545995a603p-3;
    const double d_s2 = 0x1.1107605230bc4p-7;
    const double d_s3 = -0x1.994eb3774cf24p-13;

    asm volatile(
        // ===== prologue: bank A <- E(1); s41 <- id(2); s40 = 1 =====
        "s_lshl_b32 s44, %[id1], 14\n\t"
        "s_add_u32 s46, %[tlo], s44\n\t"
        "s_addc_u32 s47, %[thi], 0\n\t"
        GLDA_Q0 GLDA_Q1 GLDA_Q2 GLDA_Q3
        "s_mov_b32 s41, %[id2]\n\t"
        "s_mov_b32 s40, 1\n\t"

        "T2V_LOOP:\n\t"
        // ---- step A (odd s): chain bank A; issue bank B <- E(s+1) ----
        BASECALC
        COS_A GLDB_Q0
        COS_B GLDB_Q1
        COS_C GLDB_Q2
        COS_D GLDB_Q3
        IDLOAD
        COS_E
        "s_waitcnt vmcnt(16)\n\t"       // bank A (oldest 16) retired
        CHAIN_A
        "s_addk_i32 s40, 1\n\t"
        // ---- step B (even s): chain bank B; issue bank A <- E(s+1) ----
        BASECALC
        COS_A GLDA_Q0
        COS_B GLDA_Q1
        COS_C GLDA_Q2
        COS_D GLDA_Q3
        IDLOAD
        COS_E
        "s_waitcnt vmcnt(16)\n\t"       // bank B (oldest 16) retired
        CHAIN_B
        "s_addk_i32 s40, 1\n\t"
        "s_cmpk_lt_i32 s40, 0x1FFF\n\t" // loop while s40 < 8191
        "s_cbranch_scc1 T2V_LOOP\n\t"
        // ---- tail step 8191 (bank A; loaded at step 8190) ----
        "s_waitcnt lgkmcnt(0)\n\t"
        COS_A COS_B COS_C COS_D COS_E
        "s_waitcnt vmcnt(0)\n\t"
        CHAIN_A
        "s_waitcnt vmcnt(0) lgkmcnt(0)\n\t"
        : [acc] "+v"(acc), [vra] "+v"(vra)
        : [tlo] "s"(tlo), [thi] "s"(thi), [bids] "s"(bids),
          [vo0] "v"(vo0), [vo1] "v"(vo1), [vo2] "v"(vo2), [vo3] "v"(vo3),
          [id1] "s"(id1), [id2] "s"(id2),
          [hpinv] "s"(d_hpinv), [hpi] "s"(d_hpi), [c4] "s"(d_c4),
          [c1] "s"(d_c1), [c2] "s"(d_c2), [s1] "s"(d_s1), [s3] "s"(d_s3),
          [c3] "v"(d_c3), [c0] "v"(d_c0), [s2] "v"(d_s2)
        : "memory", "scc", "vcc",
          "s40","s41","s42","s43","s44","s45","s46","s47",
          "s50","s51","s52","s53","s54","s55","s56","s57",
          "v8","v9","v10","v11","v12","v13","v14","v15","v16","v17",
          "v18","v19","v20","v21","v22","v23","v24","v25","v26","v27",
          "v64","v65","v66","v67","v68","v69","v70","v71",
          "v72","v73","v74","v75","v76","v77","v78","v79",
          "v80","v81","v82","v83","v84","v85","v86","v87",
          "v88","v89","v90","v91","v92","v93","v94","v95",
          "v96","v97","v98","v99","v100","v101","v102","v103",
          "v104","v105","v106","v107","v108","v109","v110","v111",
          "v112","v113","v114","v115","v116","v117","v118","v119",
          "v120","v121","v122","v123","v124","v125","v126","v127",
          "v160","v161","v162","v163","v164","v165","v166","v167",
          "v168","v169","v170","v171","v172","v173","v174","v175",
          "v176","v177","v178","v179","v180","v181","v182","v183",
          "v184","v185","v186","v187","v188","v189","v190","v191",
          "v192","v193","v194","v195","v196","v197","v198","v199",
          "v200","v201","v202","v203","v204","v205","v206","v207",
          "v208","v209","v210","v211","v212","v213","v214","v215",
          "v216","v217","v218","v219","v220","v221","v222","v223");

    // final cos + store (proven C replica, bit-identical to the asm port)
    vra = host_cosf(acc);
    out[b * (DD * DD) + r * DD + lane] = vra;
}

extern "C" void kernel_launch(void* const* d_in, const int* in_sizes, int n_in,
                              void* d_out, int out_size, void* d_ws, size_t ws_size,
                              hipStream_t stream)
{
    const int*   ids = (const int*)  d_in[0];   // [B, S] int32
    const float* emb = (const float*)d_in[1];   // [V, D*D] f32
    float*       out = (float*)      d_out;     // [B, D, D] f32
    float*       embT = (float*)     d_ws;      // V*4096 floats (1.5 MB)

    const int V = in_sizes[1] / (DD * DD);

    transpose_kernel<<<dim3(V), dim3(256), 0, stream>>>(emb, embT);
    text2vec_kernel<<<dim3(BB * DD), dim3(DD), 0, stream>>>(ids, emb, embT, out);
}